// Round 7
// baseline (360.071 us; speedup 1.0000x reference)
//
#include <hip/hip_runtime.h>

// BNN conv3d forward: x (8,32,16,160,160) f32, w (32,32,1,3,3) f32
// out[n,o,d,h,w] = sum_i sum_{kh,kw} x[n,i,d,h+kh-1,w+kw-1] * we[o,i,kh,kw]
// we = (mean|w| over taps) * sign(w).  Implicit GEMM, mfma_f32_16x16x32_f16.
//
// Round-7: occupancy/duty-cycle attack. Little's law says sustained read BW
// needs ~22KB/CU continuously outstanding; 2-block residency + burst loads
// gave ~6KB average (=> the invariant 3-3.5 TB/s of rounds 1-6). Now:
// TH=2 full-row tile, LDS = 4r x 160w x 32ch f16 = 40960 B -> 4 blocks/CU.
// 320-thr blocks; 16 float4 loads/thread issued at entry; 1 barrier.
// No halo columns in LDS: the 2 edge A-fragments are zeroed via select.
// XCD-chunked remap keeps h-neighbors on one XCD (L2 halo sharing).

typedef _Float16 half8 __attribute__((ext_vector_type(8)));
typedef float    floatx4 __attribute__((ext_vector_type(4)));

#define DHW  409600   // 16*160*160
#define HW   25600    // 160*160

__device__ __forceinline__ int lds_half_idx(int r, int w, int kg) {
    // round-5-verified swizzle family: 64B-cell swap + 16B sub-block XOR
    const int wx  = w ^ ((w >> 2) & 1);
    const int skg = kg ^ (((w >> 1) ^ (w >> 3)) & 3);
    return (r * 160 + wx) * 32 + skg * 8;
}

__device__ __forceinline__ void barrier_raw() {
    // LDS-visibility barrier that does NOT drain vmcnt
    __builtin_amdgcn_sched_barrier(0);
    asm volatile("s_waitcnt lgkmcnt(0)" ::: "memory");
    __builtin_amdgcn_s_barrier();
    __builtin_amdgcn_sched_barrier(0);
}

// ---- kernel 1: effective-weight fragments -> ws (18 KB) -------------------
// ws[((t*2+p)*64 + l)*8 + j] = we[o=p*16+(l&15)][i=(l>>4)*8+j][t]
__global__ void bnn_wprep_kernel(const float* __restrict__ w,
                                 _Float16* __restrict__ ws) {
    const int tid = threadIdx.x;
    #pragma unroll
    for (int p4 = 0; p4 < 4; ++p4) {
        const int oi = tid * 4 + p4;
        const int o  = oi >> 5;
        const int i  = oi & 31;
        const float* wp = w + oi * 9;
        float s = 0.f;
        #pragma unroll
        for (int t = 0; t < 9; ++t) s += fabsf(wp[t]);
        s *= (1.f / 9.f);
        const int l = ((i >> 3) << 4) | (o & 15);
        const int p = o >> 4;
        const int j = i & 7;
        #pragma unroll
        for (int t = 0; t < 9; ++t) {
            const float v  = wp[t];
            const float sg = (v > 0.f) ? 1.f : ((v < 0.f) ? -1.f : 0.f);
            ws[((t * 2 + p) * 64 + l) * 8 + j] = (_Float16)(s * sg);
        }
    }
}

// ---- kernel 2: the conv ---------------------------------------------------
__global__ __launch_bounds__(320, 5) void bnn_conv3d_kernel(
        const float* __restrict__ x, const _Float16* __restrict__ ws,
        float* __restrict__ out) {
    __shared__ __align__(16) _Float16 ldsh[4 * 160 * 32];   // 40960 B exact

    const int tid  = threadIdx.x;
    const int lane = tid & 63;
    const int wid  = tid >> 6;         // 0..4

    // XCD-chunked remap: consecutive work ids (h-neighbors) share an XCD.
    // 10240 = 8 * 1280, bijective.
    const int bid = blockIdx.x;
    const int wk  = (bid & 7) * 1280 + (bid >> 3);
    const int ht  = wk % 80;
    const int nd  = wk / 80;
    const int d   = nd & 15;
    const int n   = nd >> 4;
    const int h0  = ht * 2;           // block owns output rows h0, h0+1

    // ---------- staging: 640 items = (r:4, kg:4, wq:40), 2 per thread ------
    const int wq0 = tid % 40, kg0 = (tid / 40) & 3, r0 = tid / 160;
    const int id1 = tid + 320;
    const int wq1 = id1 % 40, kg1 = (id1 / 40) & 3, r1 = id1 / 160;
    const int hi0 = h0 - 1 + r0;       // input rows h0-1 .. h0+2
    const int hi1 = h0 - 1 + r1;

    const floatx4 z4 = {0.f, 0.f, 0.f, 0.f};
    floatx4 fl0[8], fl1[8];
    {
        const float* s0 = x + ((n * 32 + kg0 * 8) * 16 + d) * HW + hi0 * 160 + wq0 * 4;
        const bool ok0 = (unsigned)hi0 < 160u;
        #pragma unroll
        for (int c = 0; c < 8; ++c)
            fl0[c] = ok0 ? *reinterpret_cast<const floatx4*>(s0 + c * DHW) : z4;
        const float* s1 = x + ((n * 32 + kg1 * 8) * 16 + d) * HW + hi1 * 160 + wq1 * 4;
        const bool ok1 = (unsigned)hi1 < 160u;
        #pragma unroll
        for (int c = 0; c < 8; ++c)
            fl1[c] = ok1 ? *reinterpret_cast<const floatx4*>(s1 + c * DHW) : z4;
    }
    __builtin_amdgcn_sched_barrier(0);   // keep all 16 loads issued up front

    // ---------- pack + ds_write as loads drain -----------------------------
    #pragma unroll
    for (int u = 0; u < 4; ++u) {
        half8 pk;
        #pragma unroll
        for (int c = 0; c < 8; ++c) pk[c] = (_Float16)fl0[c][u];
        *reinterpret_cast<half8*>(&ldsh[lds_half_idx(r0, wq0 * 4 + u, kg0)]) = pk;
    }
    #pragma unroll
    for (int u = 0; u < 4; ++u) {
        half8 pk;
        #pragma unroll
        for (int c = 0; c < 8; ++c) pk[c] = (_Float16)fl1[c][u];
        *reinterpret_cast<half8*>(&ldsh[lds_half_idx(r1, wq1 * 4 + u, kg1)]) = pk;
    }
    __builtin_amdgcn_sched_barrier(0);   // wf loads must not hoist above packs

    // ---------- weight fragments (L2-resident table) -----------------------
    half8 wf0[9], wf1[9];
    {
        const half8* fb = reinterpret_cast<const half8*>(ws);
        #pragma unroll
        for (int t = 0; t < 9; ++t) {
            wf0[t] = fb[(t * 2 + 0) * 64 + lane];
            wf1[t] = fb[(t * 2 + 1) * 64 + lane];
        }
    }
    barrier_raw();     // the ONLY barrier (lgkm only; wf loads stay in flight)

    // ---------- compute: wave = 4 units (rl:2 x g in {wid, wid+5}) ---------
    // A-frag: lane l elem j = x_lds(r=rl+kh, w=g*16+(l&15)+kw-1, ch=(l>>4)*8+j)
    // D: w offset = (l>>4)*4+reg, out channel = (l&15) (+16 per otile)
    const int s16  = lane & 15;
    const int kg_r = lane >> 4;
    const half8 zh = {};
    float* ob = out + (n * 32 + s16) * DHW + d * HW + kg_r * 4;

    #pragma unroll
    for (int q = 0; q < 2; ++q) {
        const int g = wid + q * 5;           // wtile 0..9
        #pragma unroll
        for (int rl = 0; rl < 2; ++rl) {
            floatx4 a0 = z4, a1 = z4;
            #pragma unroll
            for (int kh = 0; kh < 3; ++kh) {
                #pragma unroll
                for (int kw = 0; kw < 3; ++kw) {
                    const int w_in = g * 16 + s16 + kw - 1;
                    half8 a;
                    if ((q == 0 && kw == 0) || (q == 1 && kw == 2)) {
                        // only lanes at image edge can go OOB here
                        const bool ok = (unsigned)w_in < 160u;
                        const int wrd = ok ? w_in : (w_in < 0 ? 0 : 159);
                        a = *reinterpret_cast<const half8*>(
                                &ldsh[lds_half_idx(rl + kh, wrd, kg_r)]);
                        a = ok ? a : zh;
                    } else {
                        a = *reinterpret_cast<const half8*>(
                                &ldsh[lds_half_idx(rl + kh, w_in, kg_r)]);
                    }
                    const int t = kh * 3 + kw;
                    a0 = __builtin_amdgcn_mfma_f32_16x16x32_f16(a, wf0[t], a0, 0, 0, 0);
                    a1 = __builtin_amdgcn_mfma_f32_16x16x32_f16(a, wf1[t], a1, 0, 0, 0);
                }
            }
            float* op = ob + (h0 + rl) * 160 + g * 16;
            *reinterpret_cast<floatx4*>(op)            = a0;  // o 0..15
            *reinterpret_cast<floatx4*>(op + 16 * DHW) = a1;  // o 16..31
        }
    }
}

extern "C" void kernel_launch(void* const* d_in, const int* in_sizes, int n_in,
                              void* d_out, int out_size, void* d_ws, size_t ws_size,
                              hipStream_t stream) {
    const float* x = (const float*)d_in[0];
    const float* w = (const float*)d_in[1];
    float* out = (float*)d_out;
    _Float16* ws = (_Float16*)d_ws;     // 9216 halfs = 18 KB scratch
    bnn_wprep_kernel<<<dim3(1), dim3(256), 0, stream>>>(w, ws);
    // grid: 8 n * 16 d * 80 h-tiles of 2 rows, XCD-chunk-remapped in-kernel
    bnn_conv3d_kernel<<<dim3(10240), dim3(320), 0, stream>>>(x, ws, out);
}